// Round 14
// baseline (1713.982 us; speedup 1.0000x reference)
//
#include <hip/hip_runtime.h>
#include <hip/hip_bf16.h>
#include <math.h>
#include <stdint.h>

#define L      12
#define H      12
#define DMODEL 768
#define HDIM   64
#define DFF    3072
#define VOCAB  50257
#define VPAD2  50432   // 394*128 = 197*256
#define SEQ    512
#define BATCH  4
#define MTOK   2048    // BATCH*SEQ
#define BKK    64

typedef __hip_bfloat16 bf16;
typedef __bf16 bf16x8 __attribute__((ext_vector_type(8)));
typedef float  f32x4  __attribute__((ext_vector_type(4)));

__device__ inline unsigned int f2bf_bits(float f) {
    __hip_bfloat16 h = __float2bfloat16(f);
    return (unsigned int)__builtin_bit_cast(unsigned short, h);
}

typedef __attribute__((address_space(1))) unsigned int as1_uint;
typedef __attribute__((address_space(3))) unsigned int as3_uint;

__device__ inline void load_lds_16B(const void* g, void* l) {
    __builtin_amdgcn_global_load_lds((as1_uint*)(uintptr_t)g,
                                     (as3_uint*)(uintptr_t)l, 16, 0, 0);
}

// XCD-chunked bijective swizzle (nwg % 8 == 0 for every grid we launch)
__device__ inline int xcd_swz(int raw, int nwg) {
    return (raw & 7) * (nwg >> 3) + (raw >> 3);
}

// ====== single-launch f32 -> bf16 conversion + fused embed+LN (blocks<512) ====
struct CvtP {
    const float* src[7];
    bf16* dst[7];
    long ns[7];
    long nt[7];
    const int* tokens;
    const float *E, *Pp, *g1, *b1;
    float* x;
    bf16* hbuf;
};

__global__ void cvt_all_kernel(CvtP c) {
    long gid0 = ((long)blockIdx.x * blockDim.x + threadIdx.x) * 8;
    long gstr = (long)gridDim.x * blockDim.x * 8;
    for (int s = 0; s < 7; s++) {
        const float* src = c.src[s];
        bf16* dst = c.dst[s];
        long ns = c.ns[s], ntt = c.nt[s];
        for (long i8 = gid0; i8 < ntt; i8 += gstr) {
            uint4 out;
            if (i8 < ns) {
                float4 a = *reinterpret_cast<const float4*>(src + i8);
                float4 b = *reinterpret_cast<const float4*>(src + i8 + 4);
                out.x = f2bf_bits(a.x) | (f2bf_bits(a.y) << 16);
                out.y = f2bf_bits(a.z) | (f2bf_bits(a.w) << 16);
                out.z = f2bf_bits(b.x) | (f2bf_bits(b.y) << 16);
                out.w = f2bf_bits(b.z) | (f2bf_bits(b.w) << 16);
            } else {
                out = (uint4){0u, 0u, 0u, 0u};
            }
            *reinterpret_cast<uint4*>(dst + i8) = out;
        }
    }
    // ---- fused embedding + LayerNorm (wave per row) ----
    if (blockIdx.x < MTOK / 4) {
        int wave = threadIdx.x >> 6, lane = threadIdx.x & 63;
        int row = blockIdx.x * 4 + wave;
        int s = row & (SEQ - 1);
        long ebase = (long)c.tokens[row] * 192;
        const float4* E4 = (const float4*)c.E;
        const float4* P4 = (const float4*)c.Pp;
        float4 v[3];
        float s1 = 0.f, s2 = 0.f;
        #pragma unroll
        for (int e = 0; e < 3; e++) {
            int c4 = e * 64 + lane;
            float4 a = E4[ebase + c4];
            float4 p = P4[s * 192 + c4];
            a.x += p.x; a.y += p.y; a.z += p.z; a.w += p.w;
            v[e] = a;
            ((float4*)c.x)[(size_t)row * 192 + c4] = a;
            s1 += a.x + a.y + a.z + a.w;
            s2 += a.x * a.x + a.y * a.y + a.z * a.z + a.w * a.w;
        }
        #pragma unroll
        for (int o = 32; o > 0; o >>= 1) {
            s1 += __shfl_xor(s1, o);
            s2 += __shfl_xor(s2, o);
        }
        float u    = s1 * (1.f / DMODEL);
        float var  = s2 * (1.f / DMODEL) - u * u;
        float rstd = rsqrtf(var + 1e-5f);
        #pragma unroll
        for (int e = 0; e < 3; e++) {
            int c4 = e * 64 + lane;
            float4 gg = ((const float4*)c.g1)[c4];
            float4 bb = ((const float4*)c.b1)[c4];
            float y0 = gg.x * (v[e].x - u) * rstd + bb.x;
            float y1 = gg.y * (v[e].y - u) * rstd + bb.y;
            float y2 = gg.z * (v[e].z - u) * rstd + bb.z;
            float y3 = gg.w * (v[e].w - u) * rstd + bb.w;
            uint2 o2;
            o2.x = f2bf_bits(y0) | (f2bf_bits(y1) << 16);
            o2.y = f2bf_bits(y2) | (f2bf_bits(y3) << 16);
            ((uint2*)c.hbuf)[(size_t)row * 192 + c4] = o2;
        }
    }
}

// ------- fused split-K reduce + bias + residual add + LayerNorm -> bf16 -------
__global__ __launch_bounds__(256) void reduce_ln_kernel(
        float* __restrict__ x, const float* __restrict__ part, int S,
        const float* __restrict__ bias, const float* __restrict__ g,
        const float* __restrict__ b, bf16* __restrict__ hout) {
    int wave = threadIdx.x >> 6, lane = threadIdx.x & 63;
    int row = blockIdx.x * 4 + wave;
    const float4* part4 = (const float4*)part;
    float4 v[3];
    float s1 = 0.f, s2 = 0.f;
    #pragma unroll
    for (int e = 0; e < 3; e++) {
        int c4 = e * 64 + lane;
        size_t idx = (size_t)row * 192 + c4;
        float4 a = ((const float4*)x)[idx];
        float4 bi = ((const float4*)bias)[c4];
        a.x += bi.x; a.y += bi.y; a.z += bi.z; a.w += bi.w;
        for (int sl = 0; sl < S; sl++) {
            float4 p = part4[((size_t)sl * MTOK + row) * 192 + c4];
            a.x += p.x; a.y += p.y; a.z += p.z; a.w += p.w;
        }
        v[e] = a;
        ((float4*)x)[idx] = a;
        s1 += a.x + a.y + a.z + a.w;
        s2 += a.x * a.x + a.y * a.y + a.z * a.z + a.w * a.w;
    }
    #pragma unroll
    for (int o = 32; o > 0; o >>= 1) {
        s1 += __shfl_xor(s1, o);
        s2 += __shfl_xor(s2, o);
    }
    float u    = s1 * (1.f / DMODEL);
    float var  = s2 * (1.f / DMODEL) - u * u;
    float rstd = rsqrtf(var + 1e-5f);
    #pragma unroll
    for (int e = 0; e < 3; e++) {
        int c4 = e * 64 + lane;
        float4 gg = ((const float4*)g)[c4];
        float4 bb = ((const float4*)b)[c4];
        float y0 = gg.x * (v[e].x - u) * rstd + bb.x;
        float y1 = gg.y * (v[e].y - u) * rstd + bb.y;
        float y2 = gg.z * (v[e].z - u) * rstd + bb.z;
        float y3 = gg.w * (v[e].w - u) * rstd + bb.w;
        uint2 o2;
        o2.x = f2bf_bits(y0) | (f2bf_bits(y1) << 16);
        o2.y = f2bf_bits(y2) | (f2bf_bits(y3) << 16);
        ((uint2*)hout)[(size_t)row * 192 + c4] = o2;
    }
}

// ---------------- GEMM: C[M,N] = A[M,K] * B[N,K]^T  (bf16 in, f32 acc) --------
// Unified ring-2, counted vmcnt, setprio around MFMA (round-7 proven config).
// EPI 0: C bf16, z-batched B+C (QKV)
// EPI 2: C bf16 = gelu(acc+bias)            (FF1)
// EPI 3: C f32, col-bounded to Nstore       (LM head fallback)
// EPI 4: C f32 partial [z][M][N]            (split-K; proj / FF2)
#define BM 128

template<int BN_, int EPI>
__global__ __launch_bounds__(256) void gemm_bt(
    const bf16* __restrict__ A, const bf16* __restrict__ Bmat, long strideBz,
    void* __restrict__ Cout, long strideCz,
    const float* __restrict__ bias,
    int Mm, int Nn, int Kk, int Nstore, int kslice)
{
    constexpr int NF = BN_ / 32;
    __shared__ __align__(16) bf16 As[2][BM * BKK];
    __shared__ __align__(16) bf16 Bs[2][BN_ * BKK];
    int tid = threadIdx.x;
    int lane = tid & 63, wave = tid >> 6;

    int Mtiles = Mm / BM;
    int id = xcd_swz(blockIdx.x, gridDim.x);
    int bm = (id % Mtiles) * BM;
    int bn = (id / Mtiles) * BN_;
    int z = blockIdx.z;
    const bf16* Bz = Bmat + (size_t)z * strideBz;
    int wr = (wave >> 1) * 64, wc = (wave & 1) * (BN_ / 2);

    int k0 = (EPI == 4) ? z * kslice : 0;
    int nt = ((EPI == 4) ? kslice : Kk) / BKK;

    f32x4 acc[4][NF];
    #pragma unroll
    for (int i = 0; i < 4; i++)
        #pragma unroll
        for (int j = 0; j < NF; j++) acc[i][j] = (f32x4){0.f, 0.f, 0.f, 0.f};

    auto stage = [&](int slot, int kt) {
        #pragma unroll
        for (int i = 0; i < 4; i++) {
            int byte = i * 4096 + tid * 16;
            int r = byte >> 7;
            int scb = (byte & 127) ^ ((r & 7) << 4);
            load_lds_16B(A + (size_t)(bm + r) * Kk + kt + (scb >> 1),
                         (char*)As[slot] + byte);
        }
        #pragma unroll
        for (int i = 0; i < BN_ / 32; i++) {
            int byte = i * 4096 + tid * 16;
            int r = byte >> 7;
            int scb = (byte & 127) ^ ((r & 7) << 4);
            load_lds_16B(Bz + (size_t)(bn + r) * Kk + kt + (scb >> 1),
                         (char*)Bs[slot] + byte);
        }
    };

    const int swz_rd = (lane & 7) << 4;
    stage(0, k0);
    for (int t = 0; t < nt; ++t) {
        if (t + 1 < nt) {
            stage((t + 1) & 1, k0 + (t + 1) * BKK);
            if constexpr (BN_ == 128) {
                asm volatile("s_waitcnt vmcnt(8)" ::: "memory");
            } else {
                asm volatile("s_waitcnt vmcnt(6)" ::: "memory");
            }
        } else {
            asm volatile("s_waitcnt vmcnt(0)" ::: "memory");
        }
        __builtin_amdgcn_s_barrier();
        __builtin_amdgcn_sched_barrier(0);
        __builtin_amdgcn_s_setprio(1);
        int cur = t & 1;
        #pragma unroll
        for (int kk = 0; kk < 2; ++kk) {
            bf16x8 af[4], bfr[NF];
            int ro = lane & 15;
            int cob = kk * 64 + (lane >> 4) * 16;
            #pragma unroll
            for (int mi = 0; mi < 4; mi++) {
                int row = wr + mi * 16 + ro;
                af[mi] = *reinterpret_cast<const bf16x8*>(
                    (const char*)As[cur] + row * 128 + (cob ^ swz_rd));
            }
            #pragma unroll
            for (int ni = 0; ni < NF; ni++) {
                int row = wc + ni * 16 + ro;
                bfr[ni] = *reinterpret_cast<const bf16x8*>(
                    (const char*)Bs[cur] + row * 128 + (cob ^ swz_rd));
            }
            #pragma unroll
            for (int mi = 0; mi < 4; mi++)
                #pragma unroll
                for (int ni = 0; ni < NF; ni++)
                    acc[mi][ni] = __builtin_amdgcn_mfma_f32_16x16x32_bf16(
                        af[mi], bfr[ni], acc[mi][ni], 0, 0, 0);
        }
        __builtin_amdgcn_s_setprio(0);
        __builtin_amdgcn_s_barrier();
    }

    int rbase = bm + wr + ((lane >> 4) << 2);
    int cbase = bn + wc + (lane & 15);
    #pragma unroll
    for (int mi = 0; mi < 4; mi++) {
        #pragma unroll
        for (int ni = 0; ni < NF; ni++) {
            int col = cbase + ni * 16;
            #pragma unroll
            for (int r = 0; r < 4; r++) {
                int row = rbase + mi * 16 + r;
                float v = acc[mi][ni][r];
                if constexpr (EPI == 0) {
                    ((bf16*)Cout)[(size_t)z * strideCz + (size_t)row * Nn + col] =
                        __float2bfloat16(v);
                } else if constexpr (EPI == 2) {
                    float t2 = v + bias[col];
                    float gel = 0.5f * t2 * (1.f + erff(t2 * 0.70710678118654752f));
                    ((bf16*)Cout)[(size_t)row * Nn + col] = __float2bfloat16(gel);
                } else if constexpr (EPI == 3) {
                    if (col < Nstore)
                        ((float*)Cout)[(size_t)row * Nstore + col] = v;
                } else { // EPI == 4
                    ((float*)Cout)[(size_t)z * strideCz + (size_t)row * Nn + col] = v;
                }
            }
        }
    }
}

// ======= LM head: 256x256 tile, 8 waves (2M x 4N), 8-phase / 2 K-tiles ========
// SINGLE vmcnt per K-tile (m201 discipline): stage order per tile k is
// ph0->B0(k+1), ph1->A1(k+1), ph2->B1(k+1), ph3->A0(k+2). FIFO at tile-k ph0:
// [A1(k),B0(k)... wait precisely: outstanding = B0(k),A1(k),B1(k),A0(k+1)] ->
// vmcnt(2) leaves A0(k+1); all tile-k halves done. Last tile: vmcnt(0).
// Overwrite safety: ph0 stage hits slot^1 (readers done at ph0 barrier: all
// waves completed tile k-1); ph3 stage hits slot A-h0 (its only reader is ph0,
// all waves past ph3 barrier completed ph0-ph2).
#define H8P_READ_A(mq_)                                                        \
    _Pragma("unroll")                                                          \
    for (int mi = 0; mi < 4; mi++) {                                           \
        int row = wm * 64 + mi * 16 + ro;                                      \
        _Pragma("unroll")                                                      \
        for (int kk = 0; kk < 2; kk++) {                                       \
            af[mq_][mi][kk] = *reinterpret_cast<const bf16x8*>(                \
                smem + (slot * 2 + mq_) * 16384 + row * 128 +                  \
                ((kk * 64 + cg16) ^ ((row & 7) << 4)));                        \
        }                                                                      \
    }

#define H8P_READ_B(nq_)                                                       \
    _Pragma("unroll")                                                          \
    for (int ni = 0; ni < 2; ni++) {                                           \
        int row = wn * 32 + ni * 16 + ro;                                      \
        _Pragma("unroll")                                                      \
        for (int kk = 0; kk < 2; kk++) {                                       \
            bfr[nq_][ni][kk] = *reinterpret_cast<const bf16x8*>(               \
                smem + 65536 + (slot * 2 + nq_) * 16384 + row * 128 +          \
                ((kk * 64 + cg16) ^ ((row & 7) << 4)));                        \
        }                                                                      \
    }

#define H8P_MFMA(mq_, nq_)                                                     \
    __builtin_amdgcn_s_setprio(1);                                             \
    _Pragma("unroll")                                                          \
    for (int kk = 0; kk < 2; kk++)                                             \
        _Pragma("unroll")                                                      \
        for (int mi = 0; mi < 4; mi++)                                         \
            _Pragma("unroll")                                                  \
            for (int ni = 0; ni < 2; ni++)                                     \
                acc[mq_][nq_][mi][ni] = __builtin_amdgcn_mfma_f32_16x16x32_bf16( \
                    af[mq_][mi][kk], bfr[nq_][ni][kk], acc[mq_][nq_][mi][ni],  \
                    0, 0, 0);                                                  \
    __builtin_amdgcn_s_setprio(0);

__global__ void __launch_bounds__(512, 2) gemm_head8p(
    const bf16* __restrict__ A, const bf16* __restrict__ Bmat,
    float* __restrict__ Cout, int Nstore)
{
    extern __shared__ char smem[];
    const int Kk = DMODEL;
    const int nt = Kk / BKK;                 // 12
    int tid = threadIdx.x;
    int lane = tid & 63, wave = tid >> 6;    // 8 waves
    int wm = wave >> 2, wn = wave & 3;       // 2M x 4N
    int id = xcd_swz(blockIdx.x, gridDim.x);
    int bm = (id & 7) * 256;                 // M-tiles = 8, M-fastest
    int bn = (id >> 3) * 256;
    const int ro = lane & 15;
    const int cg16 = (lane >> 4) * 16;

    f32x4 acc[2][2][4][2];
    #pragma unroll
    for (int a0 = 0; a0 < 2; a0++)
        #pragma unroll
        for (int a1 = 0; a1 < 2; a1++)
            #pragma unroll
            for (int a2 = 0; a2 < 4; a2++)
                #pragma unroll
                for (int a3 = 0; a3 < 2; a3++)
                    acc[a0][a1][a2][a3] = (f32x4){0.f, 0.f, 0.f, 0.f};

    bf16x8 af[2][4][2];    // [mq][mi][kk]
    bf16x8 bfr[2][2][2];   // [nq][ni][kk]

    // half encoding: which 0=A-h0, 1=B-h0, 2=A-h1, 3=B-h1 (h = which>>1)
    auto stage_half = [&](int slot_, int kt, int which) {
        int h = which >> 1;
        #pragma unroll
        for (int i = 0; i < 2; i++) {
            int byte = i * 8192 + tid * 16;
            int r = byte >> 7;
            int scb = (byte & 127) ^ ((r & 7) << 4);
            if ((which & 1) == 0)
                load_lds_16B(A + (size_t)(bm + h * 128 + r) * Kk + kt + (scb >> 1),
                             smem + (slot_ * 2 + h) * 16384 + byte);
            else
                load_lds_16B(Bmat + (size_t)(bn + h * 128 + r) * Kk + kt + (scb >> 1),
                             smem + 65536 + (slot_ * 2 + h) * 16384 + byte);
        }
    };

    // prologue: tile 0 complete (A0,B0,A1,B1) + A-h0 of tile 1 (10 loads)
    stage_half(0, 0, 0); stage_half(0, 0, 1); stage_half(0, 0, 2); stage_half(0, 0, 3);
    if (nt > 1) stage_half(1, BKK, 0);

    for (int k = 0; k < nt; ++k) {
        int slot = k & 1, nslot = slot ^ 1;
        int kt1 = (k + 1) * BKK;
        int kt2 = (k + 2) * BKK;
        bool pf1 = (k + 1 < nt);
        bool pf2 = (k + 2 < nt);

        // ---- phase 0: (mq0,nq0) ----  single per-tile wait
        if (pf1) {
            asm volatile("s_waitcnt vmcnt(2)" ::: "memory");
        } else {
            asm volatile("s_waitcnt vmcnt(0)" ::: "memory");
        }
        __builtin_amdgcn_s_barrier();
        __builtin_amdgcn_sched_barrier(0);
        if (pf1) stage_half(nslot, kt1, 1);      // B-h0 of k+1
        H8P_READ_A(0)
        H8P_READ_B(0)
        asm volatile("s_waitcnt lgkmcnt(0)" ::: "memory");
        __builtin_amdgcn_sched_barrier(0);
        H8P_MFMA(0, 0)

        // ---- phase 1: (mq1,nq0) ----
        __builtin_amdgcn_s_barrier();
        __builtin_amdgcn_sched_barrier(0);
        if (pf1) stage_half(nslot, kt1, 2);      // A-h1 of k+1
        H8P_READ_A(1)
        asm volatile("s_waitcnt lgkmcnt(0)" ::: "memory");
        __builtin_amdgcn_sched_barrier(0);
        H8P_MFMA(1, 0)

        // ---- phase 2: (mq0,nq1) ----
        __builtin_amdgcn_s_barrier();
        __builtin_amdgcn_sched_barrier(0);
        if (pf1) stage_half(nslot, kt1, 3);      // B-h1 of k+1
        H8P_READ_B(1)
        asm volatile("s_waitcnt lgkmcnt(0)" ::: "memory");
        __builtin_amdgcn_sched_barrier(0);
        H8P_MFMA(0, 1)

        // ---- phase 3: (mq1,nq1); frags in regs; slot A-h0 free for k+2 ----
        __builtin_amdgcn_s_barrier();
        __builtin_amdgcn_sched_barrier(0);
        if (pf2) stage_half(slot, kt2, 0);       // A-h0 of k+2
        H8P_MFMA(1, 1)
    }

    #pragma unroll
    for (int mq = 0; mq < 2; mq++) {
        #pragma unroll
        for (int nq = 0; nq < 2; nq++) {
            #pragma unroll
            for (int mi = 0; mi < 4; mi++) {
                #pragma unroll
                for (int ni = 0; ni < 2; ni++) {
                    int col = bn + nq * 128 + wn * 32 + ni * 16 + (lane & 15);
                    #pragma unroll
                    for (int r = 0; r < 4; r++) {
                        int row = bm + mq * 128 + wm * 64 + mi * 16 +
                                  ((lane >> 4) << 2) + r;
                        if (col < Nstore)
                            Cout[(size_t)row * Nstore + col] = acc[mq][nq][mi][ni][r];
                    }
                }
            }
        }
    }
}

// ---------------- MFMA flash attention (double-buffered K, prefetched V) ------
#define NEGMASK -1e10f
#define SM_SCALE 0.125f

__global__ __launch_bounds__(256) void attn_kernel(
    bf16* __restrict__ o, const bf16* __restrict__ qb,
    const bf16* __restrict__ kb, const bf16* __restrict__ vb)
{
    __shared__ __align__(16) bf16 K_lds[2][64 * 64];  // ring-2, swizzled
    __shared__ __align__(16) bf16 VT_lds[64 * 64];    // [d][kv], swizzled
    __shared__ __align__(16) bf16 P_lds[4][16 * 64];  // per-wave, swizzled

    int tid = threadIdx.x;
    int wave = tid >> 6, lane = tid & 63;
    int g = lane >> 4;
    int cq = lane & 15;
    int idx = xcd_swz(blockIdx.x, gridDim.x);
    int qt = idx & 7;
    int bh = idx >> 3;
    int h = bh % H, b = bh / H;
    int q0 = qt * 64;
    const size_t base = ((size_t)b * SEQ) * DMODEL + h * HDIM;

    bf16x8 qa[2];
    #pragma unroll
    for (int kk = 0; kk < 2; kk++)
        qa[kk] = *reinterpret_cast<const bf16x8*>(
            qb + base + (size_t)(q0 + wave * 16 + cq) * DMODEL + kk * 32 + g * 8);

    int rp = tid & 31;
    int c0 = (tid >> 5) * 8;
    const bf16* vbase = vb + base + (size_t)(2 * rp) * DMODEL + c0;

    auto stageK = [&](int slot, int mt) {
        #pragma unroll
        for (int i = 0; i < 2; i++) {
            int byte = i * 4096 + tid * 16;
            int r = byte >> 7;
            int scb = (byte & 127) ^ ((r & 7) << 4);
            load_lds_16B(kb + base + (size_t)(mt + r) * DMODEL + (scb >> 1),
                         (char*)K_lds[slot] + byte);
        }
    };

    f32x4 acc_o[4];
    #pragma unroll
    for (int df = 0; df < 4; df++) acc_o[df] = (f32x4){0.f, 0.f, 0.f, 0.f};
    float m_run[4] = {-INFINITY, -INFINITY, -INFINITY, -INFINITY};
    float l_run[4] = {0.f, 0.f, 0.f, 0.f};

    int ntiles = (qt == 0) ? (SEQ / 64) : (qt + 1);

    stageK(0, 0);
    uint4 vA = *reinterpret_cast<const uint4*>(vbase);
    uint4 vB = *reinterpret_cast<const uint4*>(vbase + DMODEL);
    asm volatile("s_waitcnt vmcnt(0)" ::: "memory");

    for (int t = 0; t < ntiles; ++t) {
        int mt = t * 64;
        int s = t & 1;
        uint4 nvA, nvB;
        bool pf = (t + 1 < ntiles);
        if (pf) {
            stageK(s ^ 1, mt + 64);
            const bf16* nv = vbase + (size_t)(mt + 64) * DMODEL;
            nvA = *reinterpret_cast<const uint4*>(nv);
            nvB = *reinterpret_cast<const uint4*>(nv + DMODEL);
            asm volatile("s_waitcnt vmcnt(4)" ::: "memory");
        } else {
            asm volatile("s_waitcnt vmcnt(0)" ::: "memory");
        }
        __builtin_amdgcn_s_barrier();
        __builtin_amdgcn_sched_barrier(0);

        {
            unsigned int au[4] = {vA.x, vA.y, vA.z, vA.w};
            unsigned int bu[4] = {vB.x, vB.y, vB.z, vB.w};
            #pragma unroll
            for (int j = 0; j < 8; j++) {
                unsigned int lo = (j & 1) ? (au[j >> 1] >> 16) : (au[j >> 1] & 0xffffu);
                unsigned int hi = (j & 1) ? (bu[j >> 1] >> 16) : (bu[j >> 1] & 0xffffu);
                int d = c0 + j;
                int byte = d * 128 + ((rp * 4) ^ ((d & 7) << 4));
                *reinterpret_cast<unsigned int*>((char*)VT_lds + byte) = lo | (hi << 16);
            }
        }

        f32x4 sc[4];
        #pragma unroll
        for (int nf = 0; nf < 4; nf++) sc[nf] = (f32x4){0.f, 0.f, 0.f, 0.f};
        __builtin_amdgcn_s_setprio(1);
        #pragma unroll
        for (int kk = 0; kk < 2; kk++) {
            #pragma unroll
            for (int nf = 0; nf < 4; nf++) {
                int row = nf * 16 + cq;
                bf16x8 kf = *reinterpret_cast<const bf16x8*>(
                    (const char*)K_lds[s] + row * 128 +
                    ((kk * 64 + g * 16) ^ ((row & 7) << 4)));
                sc[nf] = __builtin_amdgcn_mfma_f32_16x16x32_bf16(qa[kk], kf, sc[nf], 0, 0, 0);
            }
        }
        __builtin_amdgcn_s_setprio(0);

        float p[4][4];
        #pragma unroll
        for (int r = 0; r < 4; r++) {
            int qg = q0 + wave * 16 + (g << 2) + r;
            float sv[4];
            float vmax = -INFINITY;
            #pragma unroll
            for (int nf = 0; nf < 4; nf++) {
                int kv = mt + nf * 16 + cq;
                float d = sc[nf][r];
                sv[nf] = (kv >= qg) ? (d + NEGMASK) * SM_SCALE : d * SM_SCALE;
                vmax = fmaxf(vmax, sv[nf]);
            }
            vmax = fmaxf(vmax, __shfl_xor(vmax, 1));
            vmax = fmaxf(vmax, __shfl_xor(vmax, 2));
            vmax = fmaxf(vmax, __shfl_xor(vmax, 4));
            vmax = fmaxf(vmax, __shfl_xor(vmax, 8));
            float nm = fmaxf(m_run[r], vmax);
            float f = __expf(m_run[r] - nm);
            m_run[r] = nm;
            float ps = 0.f;
            #pragma unroll
            for (int nf = 0; nf < 4; nf++) {
                float pv = __expf(sv[nf] - nm);
                p[nf][r] = pv;
                ps += pv;
            }
            ps += __shfl_xor(ps, 1);
            ps += __shfl_xor(ps, 2);
            ps += __shfl_xor(ps, 4);
            ps += __shfl_xor(ps, 8);
            l_run[r] = l_run[r] * f + ps;
            #pragma unroll
            for (int df = 0; df < 4; df++) acc_o[df][r] *= f;
        }

        #pragma unroll
        for (int nf = 0; nf < 4; nf++)
            #pragma unroll
            for (int r = 0; r < 4; r++) {
                int q = (g << 2) + r;
                int blog = nf * 32 + cq * 2;
                int byte = wave * 2048 + q * 128 + (blog ^ ((q & 7) << 4));
                *reinterpret_cast<unsigned short*>((char*)P_lds + byte) =
                    (unsigned short)f2bf_bits(p[nf][r]);
            }
        asm volatile("s_waitcnt lgkmcnt(0)" ::: "memory");
        __builtin_amdgcn_s_barrier();
        __builtin_amdgcn_sched_barrier(0);

        __builtin_amdgcn_s_setprio(1);
        #pragma unroll
        for (int kk = 0; kk < 2; kk++) {
            bf16x8 pa = *reinterpret_cast<const bf16x8*>(
                (const char*)P_lds + wave * 2048 + cq * 128 +
                ((kk * 64 + g * 16) ^ ((cq & 7) << 4)));
            #pragma unroll
            for (int df = 0; df < 4; df++) {
                int row = df * 16 + cq;
                bf16x8 vf = *reinterpret_cast<const bf16x8*>(
                    (const char*)VT_lds + row * 128 +
                    ((kk * 64 + g * 16) ^ ((row & 7) << 4)));
                acc_o[df] = __builtin_amdgcn_mfma_f32_16x16x32_bf16(pa, vf, acc_o[df], 0, 0, 0);
            }
        }
        __builtin_amdgcn_s_setprio(0);

        if (pf) { vA = nvA; vB = nvB; }
    }

    #pragma unroll
    for (int r = 0; r < 4; r++) {
        float inv = 1.f / l_run[r];
        int qg = q0 + wave * 16 + (g << 2) + r;
        #pragma unroll
        for (int df = 0; df < 4; df++) {
            o[base + (size_t)qg * DMODEL + df * 16 + cq] =
                __float2bfloat16(acc_o[df][r] * inv);
        }
    }
}

// ---------------- host orchestration ----------------
extern "C" void kernel_launch(void* const* d_in, const int* in_sizes, int n_in,
                              void* d_out, int out_size, void* d_ws, size_t ws_size,
                              hipStream_t stream)
{
    (void)in_sizes; (void)n_in; (void)out_size; (void)ws_size;
    const int*   tokens = (const int*)d_in[0];
    const float* E    = (const float*)d_in[1];
    const float* P    = (const float*)d_in[2];
    const float* Wq   = (const float*)d_in[3];
    const float* Wk   = (const float*)d_in[4];
    const float* Wv   = (const float*)d_in[5];
    const float* Wo   = (const float*)d_in[6];
    const float* bo   = (const float*)d_in[7];
    const float* g1   = (const float*)d_in[8];
    const float* b1   = (const float*)d_in[9];
    const float* g2   = (const float*)d_in[10];
    const float* b2   = (const float*)d_in[11];
    const float* W1   = (const float*)d_in[12];
    const float* bff1 = (const float*)d_in[13];
    const float* W2   = (const float*)d_in[14];
    const float* bff2 = (const float*)d_in[15];
    const float* gf   = (const float*)d_in[16];
    const float* bfin = (const float*)d_in[17];

    char* ws = (char*)d_ws;
    size_t off = 0;
    auto alloc = [&](size_t bytes) -> void* {
        void* p = ws + off;
        off += (bytes + 255) & ~(size_t)255;
        return p;
    };
    float* x     = (float*)alloc((size_t)MTOK * DMODEL * 4);
    bf16* hbuf   = (bf16*)alloc((size_t)MTOK * DMODEL * 2);
    bf16* qkv    = (bf16*)alloc((size_t)3 * MTOK * DMODEL * 2);
    bf16* obuf   = (bf16*)alloc((size_t)MTOK * DMODEL * 2);
    bf16* ffb    = (bf16*)alloc((size_t)MTOK * DFF * 2);
    float* part  = (float*)alloc((size_t)3 * MTOK * DMODEL * 4);
    bf16* Eb     = (bf16*)alloc((size_t)VPAD2 * DMODEL * 2);
    bf16* Wqkv_b = (bf16*)alloc((size_t)3 * L * DMODEL * DMODEL * 2);
    bf16* Wo_b   = (bf16*)alloc((size_t)L * DMODEL * DMODEL * 2);
    bf16* W1_b   = (bf16*)alloc((size_t)L * DFF * DMODEL * 2);
    bf16* W2_b   = (bf16*)alloc((size_t)L * DMODEL * DFF * 2);

    long nW = (long)L * DMODEL * DMODEL;
    long nF = (long)L * DFF * DMODEL;
    CvtP cp;
    cp.src[0] = E;  cp.dst[0] = Eb;          cp.ns[0] = (long)VOCAB * DMODEL; cp.nt[0] = (long)VPAD2 * DMODEL;
    cp.src[1] = Wq; cp.dst[1] = Wqkv_b;      cp.ns[1] = nW; cp.nt[1] = nW;
    cp.src[2] = Wk; cp.dst[2] = Wqkv_b + nW; cp.ns[2] = nW; cp.nt[2] = nW;
    cp.src[3] = Wv; cp.dst[3] = Wqkv_b + 2 * nW; cp.ns[3] = nW; cp.nt[3] = nW;
    cp.src[4] = Wo; cp.dst[4] = Wo_b;        cp.ns[4] = nW; cp.nt[4] = nW;
    cp.src[5] = W1; cp.dst[5] = W1_b;        cp.ns[5] = nF; cp.nt[5] = nF;
    cp.src[6] = W2; cp.dst[6] = W2_b;        cp.ns[6] = nF; cp.nt[6] = nF;
    cp.tokens = tokens; cp.E = E; cp.Pp = P; cp.g1 = g1; cp.b1 = b1;
    cp.x = x; cp.hbuf = hbuf;
    cvt_all_kernel<<<2048, 256, 0, stream>>>(cp);

    const long pstride = (long)MTOK * DMODEL;
    for (int l = 0; l < L; ++l) {
        gemm_bt<64, 0><<<dim3(192, 1, 3), 256, 0, stream>>>(
            hbuf, Wqkv_b + (size_t)l * DMODEL * DMODEL, nW,
            qkv, pstride, nullptr, MTOK, DMODEL, DMODEL, 0, 0);
        attn_kernel<<<BATCH * H * (SEQ / 64), 256, 0, stream>>>(
            obuf, qkv, qkv + pstride, qkv + 2 * pstride);
        gemm_bt<64, 4><<<dim3(192, 1, 3), 256, 0, stream>>>(
            obuf, Wo_b + (size_t)l * DMODEL * DMODEL, 0,
            part, pstride, nullptr, MTOK, DMODEL, DMODEL, 0, DMODEL / 3);
        reduce_ln_kernel<<<MTOK / 4, 256, 0, stream>>>(
            x, part, 3, bo + l * DMODEL, g2 + l * DMODEL, b2 + l * DMODEL, hbuf);
        gemm_bt<128, 2><<<dim3(16 * 24, 1, 1), 256, 0, stream>>>(
            hbuf, W1_b + (size_t)l * DFF * DMODEL, 0,
            ffb, 0, bff1 + l * DFF, MTOK, DFF, DMODEL, 0, 0);
        gemm_bt<64, 4><<<dim3(192, 1, 3), 256, 0, stream>>>(
            ffb, W2_b + (size_t)l * DMODEL * DFF, 0,
            part, pstride, nullptr, MTOK, DMODEL, DFF, 0, DFF / 3);
        const float* ng = (l < L - 1) ? (g1 + (l + 1) * DMODEL) : gf;
        const float* nb = (l < L - 1) ? (b1 + (l + 1) * DMODEL) : bfin;
        reduce_ln_kernel<<<MTOK / 4, 256, 0, stream>>>(
            x, part, 3, bff2 + l * DMODEL, ng, nb, hbuf);
    }

    // LM head: 256x256 8-phase, single vmcnt/K-tile (128 KB dynamic LDS);
    // fallback to proven 128x128 ring-2 if the launch configuration is rejected.
    (void)hipFuncSetAttribute((const void*)gemm_head8p,
        hipFuncAttributeMaxDynamicSharedMemorySize, 131072);
    (void)hipGetLastError();   // clear any sticky error
    gemm_head8p<<<dim3(8 * 197), 512, 131072, stream>>>(
        hbuf, Eb, (float*)d_out, VOCAB);
    if (hipGetLastError() != hipSuccess) {
        gemm_bt<128, 3><<<dim3(16 * 394, 1, 1), 256, 0, stream>>>(
            hbuf, Eb, 0, d_out, 0, nullptr, MTOK, VPAD2, DMODEL, VOCAB, 0);
    }
}

// Round 15
// 1697.251 us; speedup vs baseline: 1.0099x; 1.0099x over previous
//
#include <hip/hip_runtime.h>
#include <hip/hip_bf16.h>
#include <math.h>
#include <stdint.h>

#define L      12
#define H      12
#define DMODEL 768
#define HDIM   64
#define DFF    3072
#define VOCAB  50257
#define VPAD2  50432   // 394*128 = 197*256
#define SEQ    512
#define BATCH  4
#define MTOK   2048    // BATCH*SEQ
#define BKK    64

typedef __hip_bfloat16 bf16;
typedef __bf16 bf16x8 __attribute__((ext_vector_type(8)));
typedef float  f32x4  __attribute__((ext_vector_type(4)));

__device__ inline unsigned int f2bf_bits(float f) {
    __hip_bfloat16 h = __float2bfloat16(f);
    return (unsigned int)__builtin_bit_cast(unsigned short, h);
}

typedef __attribute__((address_space(1))) unsigned int as1_uint;
typedef __attribute__((address_space(3))) unsigned int as3_uint;

__device__ inline void load_lds_16B(const void* g, void* l) {
    __builtin_amdgcn_global_load_lds((as1_uint*)(uintptr_t)g,
                                     (as3_uint*)(uintptr_t)l, 16, 0, 0);
}

// XCD-chunked bijective swizzle (nwg % 8 == 0 for every grid we launch)
__device__ inline int xcd_swz(int raw, int nwg) {
    return (raw & 7) * (nwg >> 3) + (raw >> 3);
}

// =================== single-launch f32 -> bf16 conversion =====================
struct CvtP {
    const float* src[7];
    bf16* dst[7];
    long ns[7];
    long nt[7];
};

__global__ void cvt_all_kernel(CvtP c) {
    long gid0 = ((long)blockIdx.x * blockDim.x + threadIdx.x) * 8;
    long gstr = (long)gridDim.x * blockDim.x * 8;
    for (int s = 0; s < 7; s++) {
        const float* src = c.src[s];
        bf16* dst = c.dst[s];
        long ns = c.ns[s], ntt = c.nt[s];
        for (long i8 = gid0; i8 < ntt; i8 += gstr) {
            uint4 out;
            if (i8 < ns) {
                float4 a = *reinterpret_cast<const float4*>(src + i8);
                float4 b = *reinterpret_cast<const float4*>(src + i8 + 4);
                out.x = f2bf_bits(a.x) | (f2bf_bits(a.y) << 16);
                out.y = f2bf_bits(a.z) | (f2bf_bits(a.w) << 16);
                out.z = f2bf_bits(b.x) | (f2bf_bits(b.y) << 16);
                out.w = f2bf_bits(b.z) | (f2bf_bits(b.w) << 16);
            } else {
                out = (uint4){0u, 0u, 0u, 0u};
            }
            *reinterpret_cast<uint4*>(dst + i8) = out;
        }
    }
}

// ---------------- fused embedding + LayerNorm (wave per row, float4) ----------
__global__ __launch_bounds__(256) void embed_ln_kernel(
        float* __restrict__ x, bf16* __restrict__ hout,
        const int* __restrict__ tok, const float* __restrict__ E,
        const float* __restrict__ Pp, const float* __restrict__ g,
        const float* __restrict__ b) {
    int wave = threadIdx.x >> 6, lane = threadIdx.x & 63;
    int row = blockIdx.x * 4 + wave;
    int s = row & (SEQ - 1);
    long ebase = (long)tok[row] * 192;
    const float4* E4 = (const float4*)E;
    const float4* P4 = (const float4*)Pp;
    float4 v[3];
    float s1 = 0.f, s2 = 0.f;
    #pragma unroll
    for (int e = 0; e < 3; e++) {
        int c4 = e * 64 + lane;
        float4 a = E4[ebase + c4];
        float4 p = P4[s * 192 + c4];
        a.x += p.x; a.y += p.y; a.z += p.z; a.w += p.w;
        v[e] = a;
        ((float4*)x)[(size_t)row * 192 + c4] = a;
        s1 += a.x + a.y + a.z + a.w;
        s2 += a.x * a.x + a.y * a.y + a.z * a.z + a.w * a.w;
    }
    #pragma unroll
    for (int o = 32; o > 0; o >>= 1) {
        s1 += __shfl_xor(s1, o);
        s2 += __shfl_xor(s2, o);
    }
    float u    = s1 * (1.f / DMODEL);
    float var  = s2 * (1.f / DMODEL) - u * u;
    float rstd = rsqrtf(var + 1e-5f);
    #pragma unroll
    for (int e = 0; e < 3; e++) {
        int c4 = e * 64 + lane;
        float4 gg = ((const float4*)g)[c4];
        float4 bb = ((const float4*)b)[c4];
        float y0 = gg.x * (v[e].x - u) * rstd + bb.x;
        float y1 = gg.y * (v[e].y - u) * rstd + bb.y;
        float y2 = gg.z * (v[e].z - u) * rstd + bb.z;
        float y3 = gg.w * (v[e].w - u) * rstd + bb.w;
        uint2 o2;
        o2.x = f2bf_bits(y0) | (f2bf_bits(y1) << 16);
        o2.y = f2bf_bits(y2) | (f2bf_bits(y3) << 16);
        ((uint2*)hout)[(size_t)row * 192 + c4] = o2;
    }
}

// ------- fused split-K reduce + bias + residual add + LayerNorm -> bf16 -------
__global__ __launch_bounds__(256) void reduce_ln_kernel(
        float* __restrict__ x, const float* __restrict__ part, int S,
        const float* __restrict__ bias, const float* __restrict__ g,
        const float* __restrict__ b, bf16* __restrict__ hout) {
    int wave = threadIdx.x >> 6, lane = threadIdx.x & 63;
    int row = blockIdx.x * 4 + wave;
    const float4* part4 = (const float4*)part;
    float4 v[3];
    float s1 = 0.f, s2 = 0.f;
    #pragma unroll
    for (int e = 0; e < 3; e++) {
        int c4 = e * 64 + lane;
        size_t idx = (size_t)row * 192 + c4;
        float4 a = ((const float4*)x)[idx];
        float4 bi = ((const float4*)bias)[c4];
        a.x += bi.x; a.y += bi.y; a.z += bi.z; a.w += bi.w;
        for (int sl = 0; sl < S; sl++) {
            float4 p = part4[((size_t)sl * MTOK + row) * 192 + c4];
            a.x += p.x; a.y += p.y; a.z += p.z; a.w += p.w;
        }
        v[e] = a;
        ((float4*)x)[idx] = a;
        s1 += a.x + a.y + a.z + a.w;
        s2 += a.x * a.x + a.y * a.y + a.z * a.z + a.w * a.w;
    }
    #pragma unroll
    for (int o = 32; o > 0; o >>= 1) {
        s1 += __shfl_xor(s1, o);
        s2 += __shfl_xor(s2, o);
    }
    float u    = s1 * (1.f / DMODEL);
    float var  = s2 * (1.f / DMODEL) - u * u;
    float rstd = rsqrtf(var + 1e-5f);
    #pragma unroll
    for (int e = 0; e < 3; e++) {
        int c4 = e * 64 + lane;
        float4 gg = ((const float4*)g)[c4];
        float4 bb = ((const float4*)b)[c4];
        float y0 = gg.x * (v[e].x - u) * rstd + bb.x;
        float y1 = gg.y * (v[e].y - u) * rstd + bb.y;
        float y2 = gg.z * (v[e].z - u) * rstd + bb.z;
        float y3 = gg.w * (v[e].w - u) * rstd + bb.w;
        uint2 o2;
        o2.x = f2bf_bits(y0) | (f2bf_bits(y1) << 16);
        o2.y = f2bf_bits(y2) | (f2bf_bits(y3) << 16);
        ((uint2*)hout)[(size_t)row * 192 + c4] = o2;
    }
}

// ---------------- GEMM: C[M,N] = A[M,K] * B[N,K]^T  (bf16 in, f32 acc) --------
// Unified ring-2, counted vmcnt, setprio around MFMA (round-7 proven config).
// EPI 0: C bf16, z-batched B+C (QKV)
// EPI 2: C bf16 = gelu(acc+bias)            (FF1)
// EPI 3: C f32, col-bounded to Nstore       (LM head fallback)
// EPI 4: C f32 partial [z][M][N]            (split-K; proj / FF2)
#define BM 128

template<int BN_, int EPI>
__global__ __launch_bounds__(256) void gemm_bt(
    const bf16* __restrict__ A, const bf16* __restrict__ Bmat, long strideBz,
    void* __restrict__ Cout, long strideCz,
    const float* __restrict__ bias,
    int Mm, int Nn, int Kk, int Nstore, int kslice)
{
    constexpr int NF = BN_ / 32;
    __shared__ __align__(16) bf16 As[2][BM * BKK];
    __shared__ __align__(16) bf16 Bs[2][BN_ * BKK];
    int tid = threadIdx.x;
    int lane = tid & 63, wave = tid >> 6;

    int Mtiles = Mm / BM;
    int id = xcd_swz(blockIdx.x, gridDim.x);
    int bm = (id % Mtiles) * BM;
    int bn = (id / Mtiles) * BN_;
    int z = blockIdx.z;
    const bf16* Bz = Bmat + (size_t)z * strideBz;
    int wr = (wave >> 1) * 64, wc = (wave & 1) * (BN_ / 2);

    int k0 = (EPI == 4) ? z * kslice : 0;
    int nt = ((EPI == 4) ? kslice : Kk) / BKK;

    f32x4 acc[4][NF];
    #pragma unroll
    for (int i = 0; i < 4; i++)
        #pragma unroll
        for (int j = 0; j < NF; j++) acc[i][j] = (f32x4){0.f, 0.f, 0.f, 0.f};

    auto stage = [&](int slot, int kt) {
        #pragma unroll
        for (int i = 0; i < 4; i++) {
            int byte = i * 4096 + tid * 16;
            int r = byte >> 7;
            int scb = (byte & 127) ^ ((r & 7) << 4);
            load_lds_16B(A + (size_t)(bm + r) * Kk + kt + (scb >> 1),
                         (char*)As[slot] + byte);
        }
        #pragma unroll
        for (int i = 0; i < BN_ / 32; i++) {
            int byte = i * 4096 + tid * 16;
            int r = byte >> 7;
            int scb = (byte & 127) ^ ((r & 7) << 4);
            load_lds_16B(Bz + (size_t)(bn + r) * Kk + kt + (scb >> 1),
                         (char*)Bs[slot] + byte);
        }
    };

    const int swz_rd = (lane & 7) << 4;
    stage(0, k0);
    for (int t = 0; t < nt; ++t) {
        if (t + 1 < nt) {
            stage((t + 1) & 1, k0 + (t + 1) * BKK);
            if constexpr (BN_ == 128) {
                asm volatile("s_waitcnt vmcnt(8)" ::: "memory");
            } else {
                asm volatile("s_waitcnt vmcnt(6)" ::: "memory");
            }
        } else {
            asm volatile("s_waitcnt vmcnt(0)" ::: "memory");
        }
        __builtin_amdgcn_s_barrier();
        __builtin_amdgcn_sched_barrier(0);
        __builtin_amdgcn_s_setprio(1);
        int cur = t & 1;
        #pragma unroll
        for (int kk = 0; kk < 2; ++kk) {
            bf16x8 af[4], bfr[NF];
            int ro = lane & 15;
            int cob = kk * 64 + (lane >> 4) * 16;
            #pragma unroll
            for (int mi = 0; mi < 4; mi++) {
                int row = wr + mi * 16 + ro;
                af[mi] = *reinterpret_cast<const bf16x8*>(
                    (const char*)As[cur] + row * 128 + (cob ^ swz_rd));
            }
            #pragma unroll
            for (int ni = 0; ni < NF; ni++) {
                int row = wc + ni * 16 + ro;
                bfr[ni] = *reinterpret_cast<const bf16x8*>(
                    (const char*)Bs[cur] + row * 128 + (cob ^ swz_rd));
            }
            #pragma unroll
            for (int mi = 0; mi < 4; mi++)
                #pragma unroll
                for (int ni = 0; ni < NF; ni++)
                    acc[mi][ni] = __builtin_amdgcn_mfma_f32_16x16x32_bf16(
                        af[mi], bfr[ni], acc[mi][ni], 0, 0, 0);
        }
        __builtin_amdgcn_s_setprio(0);
        __builtin_amdgcn_s_barrier();
    }

    int rbase = bm + wr + ((lane >> 4) << 2);
    int cbase = bn + wc + (lane & 15);
    #pragma unroll
    for (int mi = 0; mi < 4; mi++) {
        #pragma unroll
        for (int ni = 0; ni < NF; ni++) {
            int col = cbase + ni * 16;
            #pragma unroll
            for (int r = 0; r < 4; r++) {
                int row = rbase + mi * 16 + r;
                float v = acc[mi][ni][r];
                if constexpr (EPI == 0) {
                    ((bf16*)Cout)[(size_t)z * strideCz + (size_t)row * Nn + col] =
                        __float2bfloat16(v);
                } else if constexpr (EPI == 2) {
                    float t2 = v + bias[col];
                    float gel = 0.5f * t2 * (1.f + erff(t2 * 0.70710678118654752f));
                    ((bf16*)Cout)[(size_t)row * Nn + col] = __float2bfloat16(gel);
                } else if constexpr (EPI == 3) {
                    if (col < Nstore)
                        ((float*)Cout)[(size_t)row * Nstore + col] = v;
                } else { // EPI == 4
                    ((float*)Cout)[(size_t)z * strideCz + (size_t)row * Nn + col] = v;
                }
            }
        }
    }
}

// ======= LM head: 256x256 tile, 8 waves (2M x 4N), 8-phase / 2 K-tiles ========
// Round-12 schedule (best measured): per-phase counted vmcnt(4), stage order
// A0,B0,A1,B1 of tile k+1 across phases 0-3; one barrier per phase; 16-MFMA
// setprio clusters. LDS 128KB: A [slot][half] 4x16KB @0; B 4x16KB @65536.
#define H8P_READ_A(mq_)                                                        \
    _Pragma("unroll")                                                          \
    for (int mi = 0; mi < 4; mi++) {                                           \
        int row = wm * 64 + mi * 16 + ro;                                      \
        _Pragma("unroll")                                                      \
        for (int kk = 0; kk < 2; kk++) {                                       \
            af[mq_][mi][kk] = *reinterpret_cast<const bf16x8*>(                \
                smem + (slot * 2 + mq_) * 16384 + row * 128 +                  \
                ((kk * 64 + cg16) ^ ((row & 7) << 4)));                        \
        }                                                                      \
    }

#define H8P_READ_B(nq_)                                                       \
    _Pragma("unroll")                                                          \
    for (int ni = 0; ni < 2; ni++) {                                           \
        int row = wn * 32 + ni * 16 + ro;                                      \
        _Pragma("unroll")                                                      \
        for (int kk = 0; kk < 2; kk++) {                                       \
            bfr[nq_][ni][kk] = *reinterpret_cast<const bf16x8*>(               \
                smem + 65536 + (slot * 2 + nq_) * 16384 + row * 128 +          \
                ((kk * 64 + cg16) ^ ((row & 7) << 4)));                        \
        }                                                                      \
    }

#define H8P_MFMA(mq_, nq_)                                                     \
    __builtin_amdgcn_s_setprio(1);                                             \
    _Pragma("unroll")                                                          \
    for (int kk = 0; kk < 2; kk++)                                             \
        _Pragma("unroll")                                                      \
        for (int mi = 0; mi < 4; mi++)                                         \
            _Pragma("unroll")                                                  \
            for (int ni = 0; ni < 2; ni++)                                     \
                acc[mq_][nq_][mi][ni] = __builtin_amdgcn_mfma_f32_16x16x32_bf16( \
                    af[mq_][mi][kk], bfr[nq_][ni][kk], acc[mq_][nq_][mi][ni],  \
                    0, 0, 0);                                                  \
    __builtin_amdgcn_s_setprio(0);

__global__ void __launch_bounds__(512, 2) gemm_head8p(
    const bf16* __restrict__ A, const bf16* __restrict__ Bmat,
    float* __restrict__ Cout, int Nstore)
{
    extern __shared__ char smem[];
    const int Kk = DMODEL;
    const int nt = Kk / BKK;                 // 12
    int tid = threadIdx.x;
    int lane = tid & 63, wave = tid >> 6;    // 8 waves
    int wm = wave >> 2, wn = wave & 3;       // 2M x 4N
    int id = xcd_swz(blockIdx.x, gridDim.x);
    int bm = (id & 7) * 256;                 // M-tiles = 8, M-fastest
    int bn = (id >> 3) * 256;
    const int ro = lane & 15;
    const int cg16 = (lane >> 4) * 16;

    f32x4 acc[2][2][4][2];
    #pragma unroll
    for (int a0 = 0; a0 < 2; a0++)
        #pragma unroll
        for (int a1 = 0; a1 < 2; a1++)
            #pragma unroll
            for (int a2 = 0; a2 < 4; a2++)
                #pragma unroll
                for (int a3 = 0; a3 < 2; a3++)
                    acc[a0][a1][a2][a3] = (f32x4){0.f, 0.f, 0.f, 0.f};

    bf16x8 af[2][4][2];    // [mq][mi][kk]
    bf16x8 bfr[2][2][2];   // [nq][ni][kk]

    auto stage_half = [&](int slot_, int kt, int which) {
        int h = which >> 1;
        #pragma unroll
        for (int i = 0; i < 2; i++) {
            int byte = i * 8192 + tid * 16;
            int r = byte >> 7;
            int scb = (byte & 127) ^ ((r & 7) << 4);
            if ((which & 1) == 0)
                load_lds_16B(A + (size_t)(bm + h * 128 + r) * Kk + kt + (scb >> 1),
                             smem + (slot_ * 2 + h) * 16384 + byte);
            else
                load_lds_16B(Bmat + (size_t)(bn + h * 128 + r) * Kk + kt + (scb >> 1),
                             smem + 65536 + (slot_ * 2 + h) * 16384 + byte);
        }
    };

    stage_half(0, 0, 0); stage_half(0, 0, 1); stage_half(0, 0, 2); stage_half(0, 0, 3);

    for (int k = 0; k < nt; ++k) {
        int slot = k & 1, nslot = slot ^ 1;
        int kt2 = (k + 1) * BKK;
        bool pf = (k + 1 < nt);

        asm volatile("s_waitcnt vmcnt(4)" ::: "memory");
        if (pf) stage_half(nslot, kt2, 0);
        __builtin_amdgcn_s_barrier();
        __builtin_amdgcn_sched_barrier(0);
        H8P_READ_A(0)
        H8P_READ_B(0)
        asm volatile("s_waitcnt lgkmcnt(0)" ::: "memory");
        __builtin_amdgcn_sched_barrier(0);
        H8P_MFMA(0, 0)

        if (pf) {
            asm volatile("s_waitcnt vmcnt(4)" ::: "memory");
        } else {
            asm volatile("s_waitcnt vmcnt(2)" ::: "memory");
        }
        if (pf) stage_half(nslot, kt2, 1);
        __builtin_amdgcn_s_barrier();
        __builtin_amdgcn_sched_barrier(0);
        H8P_READ_A(1)
        asm volatile("s_waitcnt lgkmcnt(0)" ::: "memory");
        __builtin_amdgcn_sched_barrier(0);
        H8P_MFMA(1, 0)

        if (pf) {
            asm volatile("s_waitcnt vmcnt(4)" ::: "memory");
        } else {
            asm volatile("s_waitcnt vmcnt(0)" ::: "memory");
        }
        if (pf) stage_half(nslot, kt2, 2);
        __builtin_amdgcn_s_barrier();
        __builtin_amdgcn_sched_barrier(0);
        H8P_READ_B(1)
        asm volatile("s_waitcnt lgkmcnt(0)" ::: "memory");
        __builtin_amdgcn_sched_barrier(0);
        H8P_MFMA(0, 1)

        if (pf) stage_half(nslot, kt2, 3);
        __builtin_amdgcn_s_barrier();
        __builtin_amdgcn_sched_barrier(0);
        H8P_MFMA(1, 1)
    }

    #pragma unroll
    for (int mq = 0; mq < 2; mq++) {
        #pragma unroll
        for (int nq = 0; nq < 2; nq++) {
            #pragma unroll
            for (int mi = 0; mi < 4; mi++) {
                #pragma unroll
                for (int ni = 0; ni < 2; ni++) {
                    int col = bn + nq * 128 + wn * 32 + ni * 16 + (lane & 15);
                    #pragma unroll
                    for (int r = 0; r < 4; r++) {
                        int row = bm + mq * 128 + wm * 64 + mi * 16 +
                                  ((lane >> 4) << 2) + r;
                        if (col < Nstore)
                            Cout[(size_t)row * Nstore + col] = acc[mq][nq][mi][ni][r];
                    }
                }
            }
        }
    }
}

// ---------------- MFMA flash attention (double-buffered K, prefetched V) ------
#define NEGMASK -1e10f
#define SM_SCALE 0.125f

__global__ __launch_bounds__(256) void attn_kernel(
    bf16* __restrict__ o, const bf16* __restrict__ qb,
    const bf16* __restrict__ kb, const bf16* __restrict__ vb)
{
    __shared__ __align__(16) bf16 K_lds[2][64 * 64];  // ring-2, swizzled
    __shared__ __align__(16) bf16 VT_lds[64 * 64];    // [d][kv], swizzled
    __shared__ __align__(16) bf16 P_lds[4][16 * 64];  // per-wave, swizzled

    int tid = threadIdx.x;
    int wave = tid >> 6, lane = tid & 63;
    int g = lane >> 4;
    int cq = lane & 15;
    int idx = xcd_swz(blockIdx.x, gridDim.x);
    int qt = idx & 7;
    int bh = idx >> 3;
    int h = bh % H, b = bh / H;
    int q0 = qt * 64;
    const size_t base = ((size_t)b * SEQ) * DMODEL + h * HDIM;

    bf16x8 qa[2];
    #pragma unroll
    for (int kk = 0; kk < 2; kk++)
        qa[kk] = *reinterpret_cast<const bf16x8*>(
            qb + base + (size_t)(q0 + wave * 16 + cq) * DMODEL + kk * 32 + g * 8);

    int rp = tid & 31;
    int c0 = (tid >> 5) * 8;
    const bf16* vbase = vb + base + (size_t)(2 * rp) * DMODEL + c0;

    auto stageK = [&](int slot, int mt) {
        #pragma unroll
        for (int i = 0; i < 2; i++) {
            int byte = i * 4096 + tid * 16;
            int r = byte >> 7;
            int scb = (byte & 127) ^ ((r & 7) << 4);
            load_lds_16B(kb + base + (size_t)(mt + r) * DMODEL + (scb >> 1),
                         (char*)K_lds[slot] + byte);
        }
    };

    f32x4 acc_o[4];
    #pragma unroll
    for (int df = 0; df < 4; df++) acc_o[df] = (f32x4){0.f, 0.f, 0.f, 0.f};
    float m_run[4] = {-INFINITY, -INFINITY, -INFINITY, -INFINITY};
    float l_run[4] = {0.f, 0.f, 0.f, 0.f};

    int ntiles = (qt == 0) ? (SEQ / 64) : (qt + 1);

    stageK(0, 0);
    uint4 vA = *reinterpret_cast<const uint4*>(vbase);
    uint4 vB = *reinterpret_cast<const uint4*>(vbase + DMODEL);
    asm volatile("s_waitcnt vmcnt(0)" ::: "memory");

    for (int t = 0; t < ntiles; ++t) {
        int mt = t * 64;
        int s = t & 1;
        uint4 nvA, nvB;
        bool pf = (t + 1 < ntiles);
        if (pf) {
            stageK(s ^ 1, mt + 64);
            const bf16* nv = vbase + (size_t)(mt + 64) * DMODEL;
            nvA = *reinterpret_cast<const uint4*>(nv);
            nvB = *reinterpret_cast<const uint4*>(nv + DMODEL);
            asm volatile("s_waitcnt vmcnt(4)" ::: "memory");
        } else {
            asm volatile("s_waitcnt vmcnt(0)" ::: "memory");
        }
        __builtin_amdgcn_s_barrier();
        __builtin_amdgcn_sched_barrier(0);

        {
            unsigned int au[4] = {vA.x, vA.y, vA.z, vA.w};
            unsigned int bu[4] = {vB.x, vB.y, vB.z, vB.w};
            #pragma unroll
            for (int j = 0; j < 8; j++) {
                unsigned int lo = (j & 1) ? (au[j >> 1] >> 16) : (au[j >> 1] & 0xffffu);
                unsigned int hi = (j & 1) ? (bu[j >> 1] >> 16) : (bu[j >> 1] & 0xffffu);
                int d = c0 + j;
                int byte = d * 128 + ((rp * 4) ^ ((d & 7) << 4));
                *reinterpret_cast<unsigned int*>((char*)VT_lds + byte) = lo | (hi << 16);
            }
        }

        f32x4 sc[4];
        #pragma unroll
        for (int nf = 0; nf < 4; nf++) sc[nf] = (f32x4){0.f, 0.f, 0.f, 0.f};
        __builtin_amdgcn_s_setprio(1);
        #pragma unroll
        for (int kk = 0; kk < 2; kk++) {
            #pragma unroll
            for (int nf = 0; nf < 4; nf++) {
                int row = nf * 16 + cq;
                bf16x8 kf = *reinterpret_cast<const bf16x8*>(
                    (const char*)K_lds[s] + row * 128 +
                    ((kk * 64 + g * 16) ^ ((row & 7) << 4)));
                sc[nf] = __builtin_amdgcn_mfma_f32_16x16x32_bf16(qa[kk], kf, sc[nf], 0, 0, 0);
            }
        }
        __builtin_amdgcn_s_setprio(0);

        float p[4][4];
        #pragma unroll
        for (int r = 0; r < 4; r++) {
            int qg = q0 + wave * 16 + (g << 2) + r;
            float sv[4];
            float vmax = -INFINITY;
            #pragma unroll
            for (int nf = 0; nf < 4; nf++) {
                int kv = mt + nf * 16 + cq;
                float d = sc[nf][r];
                sv[nf] = (kv >= qg) ? (d + NEGMASK) * SM_SCALE : d * SM_SCALE;
                vmax = fmaxf(vmax, sv[nf]);
            }
            vmax = fmaxf(vmax, __shfl_xor(vmax, 1));
            vmax = fmaxf(vmax, __shfl_xor(vmax, 2));
            vmax = fmaxf(vmax, __shfl_xor(vmax, 4));
            vmax = fmaxf(vmax, __shfl_xor(vmax, 8));
            float nm = fmaxf(m_run[r], vmax);
            float f = __expf(m_run[r] - nm);
            m_run[r] = nm;
            float ps = 0.f;
            #pragma unroll
            for (int nf = 0; nf < 4; nf++) {
                float pv = __expf(sv[nf] - nm);
                p[nf][r] = pv;
                ps += pv;
            }
            ps += __shfl_xor(ps, 1);
            ps += __shfl_xor(ps, 2);
            ps += __shfl_xor(ps, 4);
            ps += __shfl_xor(ps, 8);
            l_run[r] = l_run[r] * f + ps;
            #pragma unroll
            for (int df = 0; df < 4; df++) acc_o[df][r] *= f;
        }

        #pragma unroll
        for (int nf = 0; nf < 4; nf++)
            #pragma unroll
            for (int r = 0; r < 4; r++) {
                int q = (g << 2) + r;
                int blog = nf * 32 + cq * 2;
                int byte = wave * 2048 + q * 128 + (blog ^ ((q & 7) << 4));
                *reinterpret_cast<unsigned short*>((char*)P_lds + byte) =
                    (unsigned short)f2bf_bits(p[nf][r]);
            }
        asm volatile("s_waitcnt lgkmcnt(0)" ::: "memory");
        __builtin_amdgcn_s_barrier();
        __builtin_amdgcn_sched_barrier(0);

        __builtin_amdgcn_s_setprio(1);
        #pragma unroll
        for (int kk = 0; kk < 2; kk++) {
            bf16x8 pa = *reinterpret_cast<const bf16x8*>(
                (const char*)P_lds + wave * 2048 + cq * 128 +
                ((kk * 64 + g * 16) ^ ((cq & 7) << 4)));
            #pragma unroll
            for (int df = 0; df < 4; df++) {
                int row = df * 16 + cq;
                bf16x8 vf = *reinterpret_cast<const bf16x8*>(
                    (const char*)VT_lds + row * 128 +
                    ((kk * 64 + g * 16) ^ ((row & 7) << 4)));
                acc_o[df] = __builtin_amdgcn_mfma_f32_16x16x32_bf16(pa, vf, acc_o[df], 0, 0, 0);
            }
        }
        __builtin_amdgcn_s_setprio(0);

        if (pf) { vA = nvA; vB = nvB; }
    }

    #pragma unroll
    for (int r = 0; r < 4; r++) {
        float inv = 1.f / l_run[r];
        int qg = q0 + wave * 16 + (g << 2) + r;
        #pragma unroll
        for (int df = 0; df < 4; df++) {
            o[base + (size_t)qg * DMODEL + df * 16 + cq] =
                __float2bfloat16(acc_o[df][r] * inv);
        }
    }
}

// ---------------- host orchestration ----------------
extern "C" void kernel_launch(void* const* d_in, const int* in_sizes, int n_in,
                              void* d_out, int out_size, void* d_ws, size_t ws_size,
                              hipStream_t stream)
{
    (void)in_sizes; (void)n_in; (void)out_size; (void)ws_size;
    const int*   tokens = (const int*)d_in[0];
    const float* E    = (const float*)d_in[1];
    const float* P    = (const float*)d_in[2];
    const float* Wq   = (const float*)d_in[3];
    const float* Wk   = (const float*)d_in[4];
    const float* Wv   = (const float*)d_in[5];
    const float* Wo   = (const float*)d_in[6];
    const float* bo   = (const float*)d_in[7];
    const float* g1   = (const float*)d_in[8];
    const float* b1   = (const float*)d_in[9];
    const float* g2   = (const float*)d_in[10];
    const float* b2   = (const float*)d_in[11];
    const float* W1   = (const float*)d_in[12];
    const float* bff1 = (const float*)d_in[13];
    const float* W2   = (const float*)d_in[14];
    const float* bff2 = (const float*)d_in[15];
    const float* gf   = (const float*)d_in[16];
    const float* bfin = (const float*)d_in[17];

    char* ws = (char*)d_ws;
    size_t off = 0;
    auto alloc = [&](size_t bytes) -> void* {
        void* p = ws + off;
        off += (bytes + 255) & ~(size_t)255;
        return p;
    };
    float* x     = (float*)alloc((size_t)MTOK * DMODEL * 4);
    bf16* hbuf   = (bf16*)alloc((size_t)MTOK * DMODEL * 2);
    bf16* qkv    = (bf16*)alloc((size_t)3 * MTOK * DMODEL * 2);
    bf16* obuf   = (bf16*)alloc((size_t)MTOK * DMODEL * 2);
    bf16* ffb    = (bf16*)alloc((size_t)MTOK * DFF * 2);
    float* part  = (float*)alloc((size_t)3 * MTOK * DMODEL * 4);
    bf16* Eb     = (bf16*)alloc((size_t)VPAD2 * DMODEL * 2);
    bf16* Wqkv_b = (bf16*)alloc((size_t)3 * L * DMODEL * DMODEL * 2);
    bf16* Wo_b   = (bf16*)alloc((size_t)L * DMODEL * DMODEL * 2);
    bf16* W1_b   = (bf16*)alloc((size_t)L * DFF * DMODEL * 2);
    bf16* W2_b   = (bf16*)alloc((size_t)L * DMODEL * DFF * 2);

    long nW = (long)L * DMODEL * DMODEL;
    long nF = (long)L * DFF * DMODEL;
    CvtP cp;
    cp.src[0] = E;  cp.dst[0] = Eb;          cp.ns[0] = (long)VOCAB * DMODEL; cp.nt[0] = (long)VPAD2 * DMODEL;
    cp.src[1] = Wq; cp.dst[1] = Wqkv_b;      cp.ns[1] = nW; cp.nt[1] = nW;
    cp.src[2] = Wk; cp.dst[2] = Wqkv_b + nW; cp.ns[2] = nW; cp.nt[2] = nW;
    cp.src[3] = Wv; cp.dst[3] = Wqkv_b + 2 * nW; cp.ns[3] = nW; cp.nt[3] = nW;
    cp.src[4] = Wo; cp.dst[4] = Wo_b;        cp.ns[4] = nW; cp.nt[4] = nW;
    cp.src[5] = W1; cp.dst[5] = W1_b;        cp.ns[5] = nF; cp.nt[5] = nF;
    cp.src[6] = W2; cp.dst[6] = W2_b;        cp.ns[6] = nF; cp.nt[6] = nF;
    cvt_all_kernel<<<2048, 256, 0, stream>>>(cp);

    embed_ln_kernel<<<MTOK / 4, 256, 0, stream>>>(x, hbuf, tokens, E, P, g1, b1);

    const long pstride = (long)MTOK * DMODEL;
    for (int l = 0; l < L; ++l) {
        gemm_bt<64, 0><<<dim3(192, 1, 3), 256, 0, stream>>>(
            hbuf, Wqkv_b + (size_t)l * DMODEL * DMODEL, nW,
            qkv, pstride, nullptr, MTOK, DMODEL, DMODEL, 0, 0);
        attn_kernel<<<BATCH * H * (SEQ / 64), 256, 0, stream>>>(
            obuf, qkv, qkv + pstride, qkv + 2 * pstride);
        gemm_bt<64, 4><<<dim3(192, 1, 3), 256, 0, stream>>>(
            obuf, Wo_b + (size_t)l * DMODEL * DMODEL, 0,
            part, pstride, nullptr, MTOK, DMODEL, DMODEL, 0, DMODEL / 3);
        reduce_ln_kernel<<<MTOK / 4, 256, 0, stream>>>(
            x, part, 3, bo + l * DMODEL, g2 + l * DMODEL, b2 + l * DMODEL, hbuf);
        gemm_bt<128, 2><<<dim3(16 * 24, 1, 1), 256, 0, stream>>>(
            hbuf, W1_b + (size_t)l * DFF * DMODEL, 0,
            ffb, 0, bff1 + l * DFF, MTOK, DFF, DMODEL, 0, 0);
        gemm_bt<64, 4><<<dim3(192, 1, 3), 256, 0, stream>>>(
            ffb, W2_b + (size_t)l * DMODEL * DFF, 0,
            part, pstride, nullptr, MTOK, DMODEL, DFF, 0, DFF / 3);
        const float* ng = (l < L - 1) ? (g1 + (l + 1) * DMODEL) : gf;
        const float* nb = (l < L - 1) ? (b1 + (l + 1) * DMODEL) : bfin;
        reduce_ln_kernel<<<MTOK / 4, 256, 0, stream>>>(
            x, part, 3, bff2 + l * DMODEL, ng, nb, hbuf);
    }

    // LM head: 256x256 8-phase (128 KB dynamic LDS); fallback to proven
    // 128x128 ring-2 if the launch configuration is rejected.
    (void)hipFuncSetAttribute((const void*)gemm_head8p,
        hipFuncAttributeMaxDynamicSharedMemorySize, 131072);
    (void)hipGetLastError();   // clear any sticky error
    gemm_head8p<<<dim3(8 * 197), 512, 131072, stream>>>(
        hbuf, Eb, (float*)d_out, VOCAB);
    if (hipGetLastError() != hipSuccess) {
        gemm_bt<128, 3><<<dim3(16 * 394, 1, 1), 256, 0, stream>>>(
            hbuf, Eb, 0, d_out, 0, nullptr, MTOK, VPAD2, DMODEL, VOCAB, 0);
    }
}